// Round 11
// baseline (135.459 us; speedup 1.0000x reference)
//
#include <hip/hip_runtime.h>

#define DM 1024
#define BATCH 4
#define SEQ 2048
#define M_TOT (BATCH*SEQ)

typedef unsigned short ushort_t;
typedef __bf16 bf16x8 __attribute__((ext_vector_type(8)));
typedef float f32x4 __attribute__((ext_vector_type(4)));
typedef unsigned short u16x4 __attribute__((ext_vector_type(4)));
typedef unsigned short u16x8 __attribute__((ext_vector_type(8)));

__device__ __forceinline__ ushort_t f2bf(float f) {
  unsigned u = __builtin_bit_cast(unsigned, f);
  u = (u + 0x7fffu + ((u >> 16) & 1u)) >> 16;
  return (ushort_t)u;
}
__device__ __forceinline__ float bf2f(ushort_t h) {
  unsigned u = ((unsigned)h) << 16;
  return __builtin_bit_cast(float, u);
}

// async global->LDS, 16B per lane, wave-uniform LDS base + lane*16
#define GLL(gp, lp)                                                            \
  __builtin_amdgcn_global_load_lds(                                            \
      (const __attribute__((address_space(1))) unsigned int*)(const void*)(gp),\
      (__attribute__((address_space(3))) unsigned int*)(void*)(lp), 16, 0, 0)

// 4-slot swizzle for BK=32 kernels (k_small): verified R7, conflicts -> 0.
__device__ __forceinline__ size_t src_off(int row0, int e) {
  return (size_t)(row0 + (e >> 2)) * DM + (((e & 3) ^ ((e >> 3) & 3)) * 8);
}

// ---------------------------------------------------------------------------
// K1 (VECTORIZED): qr[b,:] = sum_s gqw[s]*q[b,s,:]; kr likewise;
// G = [sum gqw, sum gkw]; qb = bf16(gqw[s]*q); vb = bf16(v).
// grid (BATCH, SEQ/16), block 256; thread owns 4 consecutive cols (float4).
__global__ void k_reduce(const float* __restrict__ q, const float* __restrict__ k,
                         const float* __restrict__ v,
                         const float* __restrict__ gqw, const float* __restrict__ gkw,
                         float* __restrict__ qr, float* __restrict__ kr,
                         float* __restrict__ G,
                         ushort_t* __restrict__ qb, ushort_t* __restrict__ vb) {
  const int b = blockIdx.x, sc = blockIdx.y;
  const int d0 = threadIdx.x * 4;
  const int s0 = sc * 16;
  const size_t base = ((size_t)b * SEQ + s0) * DM + d0;
  float aqx = 0.f, aqy = 0.f, aqz = 0.f, aqw = 0.f;
  float akx = 0.f, aky = 0.f, akz = 0.f, akw = 0.f;
  float sgq = 0.f, sgk = 0.f;
#pragma unroll 4
  for (int i = 0; i < 16; ++i) {
    const float wq = gqw[s0 + i], wk = gkw[s0 + i];
    const size_t off = base + (size_t)i * DM;
    const float4 qv = *(const float4*)(q + off);
    const float4 kv = *(const float4*)(k + off);
    const float4 vv = *(const float4*)(v + off);
    aqx += wq * qv.x; aqy += wq * qv.y; aqz += wq * qv.z; aqw += wq * qv.w;
    akx += wk * kv.x; aky += wk * kv.y; akz += wk * kv.z; akw += wk * kv.w;
    u16x4 oq, ov;
    oq[0] = f2bf(wq * qv.x); oq[1] = f2bf(wq * qv.y);
    oq[2] = f2bf(wq * qv.z); oq[3] = f2bf(wq * qv.w);
    ov[0] = f2bf(vv.x); ov[1] = f2bf(vv.y); ov[2] = f2bf(vv.z); ov[3] = f2bf(vv.w);
    *(u16x4*)(qb + off) = oq;
    *(u16x4*)(vb + off) = ov;
    sgq += wq; sgk += wk;
  }
  atomicAdd(&qr[b * DM + d0 + 0], aqx);
  atomicAdd(&qr[b * DM + d0 + 1], aqy);
  atomicAdd(&qr[b * DM + d0 + 2], aqz);
  atomicAdd(&qr[b * DM + d0 + 3], aqw);
  atomicAdd(&kr[b * DM + d0 + 0], akx);
  atomicAdd(&kr[b * DM + d0 + 1], aky);
  atomicAdd(&kr[b * DM + d0 + 2], akz);
  atomicAdd(&kr[b * DM + d0 + 3], akw);
  if (b == 0 && threadIdx.x == 0) {
    atomicAdd(&G[0], sgq);
    atomicAdd(&G[1], sgk);
  }
}

// K2a: partial GEMV over K-chunks
__global__ void k_gpart(const float* __restrict__ wq, const float* __restrict__ wk,
                        const float* __restrict__ qr, const float* __restrict__ kr,
                        float* __restrict__ qacc, float* __restrict__ kacc) {
  const int d = blockIdx.x * 256 + threadIdx.x;
  const int k0 = blockIdx.y * 32;
  __shared__ float sq[4][32], sk[4][32];
  if (threadIdx.x < 128) {
    const int b = threadIdx.x >> 5, kk = threadIdx.x & 31;
    sq[b][kk] = qr[b * DM + k0 + kk];
    sk[b][kk] = kr[b * DM + k0 + kk];
  }
  __syncthreads();
  float aq[4] = {0.f, 0.f, 0.f, 0.f}, ak[4] = {0.f, 0.f, 0.f, 0.f};
#pragma unroll 8
  for (int kk = 0; kk < 32; ++kk) {
    const float wqv = wq[(size_t)(k0 + kk) * DM + d];
    const float wkv = wk[(size_t)(k0 + kk) * DM + d];
#pragma unroll
    for (int b = 0; b < 4; ++b) {
      aq[b] += sq[b][kk] * wqv;
      ak[b] += sk[b][kk] * wkv;
    }
  }
#pragma unroll
  for (int b = 0; b < 4; ++b) {
    atomicAdd(&qacc[b * DM + d], aq[b]);
    atomicAdd(&kacc[b * DM + d], ak[b]);
  }
}

// K2b: gk[b,d] = (qacc + bq[d]*G0) * (kacc + bk[d]*G1)
__global__ void k_gfin(const float* __restrict__ qacc, const float* __restrict__ kacc,
                       const float* __restrict__ bq, const float* __restrict__ bk,
                       const float* __restrict__ G, float* __restrict__ gk) {
  const int i = blockIdx.x * 256 + threadIdx.x;
  const int d = i & (DM - 1);
  const float gqv = qacc[i] + bq[d] * G[0];
  const float gkr = kacc[i] + bk[d] * G[1];
  gk[i] = gqv * gkr;
}

// K3: fp32 -> bf16 row-major convert (y=0: wq->wqB, y=1: wv->wvB)
__global__ void k_conv(const float* __restrict__ x0, ushort_t* __restrict__ y0,
                       const float* __restrict__ x1, ushort_t* __restrict__ y1) {
  const float* x = blockIdx.y ? x1 : x0;
  ushort_t* y = blockIdx.y ? y1 : y0;
  size_t i = (size_t)blockIdx.x * 256 + threadIdx.x;
  const float4* p = (const float4*)x + i * 2;
  float4 a = p[0], b = p[1];
  u16x8 o;
  o[0] = f2bf(a.x); o[1] = f2bf(a.y); o[2] = f2bf(a.z); o[3] = f2bf(a.w);
  o[4] = f2bf(b.x); o[5] = f2bf(b.y); o[6] = f2bf(b.z); o[7] = f2bf(b.w);
  *(u16x8*)(y + i * 8) = o;
}

// K4: transpose-convert wo [K][N] fp32 -> woT [N][K] bf16
__global__ void k_trans(const float* __restrict__ W, ushort_t* __restrict__ T) {
  __shared__ float ls[32][33];
  const int bi = blockIdx.x, bj = blockIdx.y;
#pragma unroll
  for (int p = 0; p < 4; ++p) {
    int e = threadIdx.x + p * 256;
    int r = e >> 5, c = e & 31;
    ls[r][c] = W[(size_t)(bi * 32 + r) * DM + bj * 32 + c];
  }
  __syncthreads();
#pragma unroll
  for (int p = 0; p < 4; ++p) {
    int e = threadIdx.x + p * 256;
    int r = e >> 5, c = e & 31;
    T[(size_t)(bj * 32 + r) * DM + bi * 32 + c] = f2bf(ls[c][r]);
  }
}

// K5: wogT[b][n][j] = woT[n][j] * gk[b][j]
__global__ void k_wog(const ushort_t* __restrict__ woT, const float* __restrict__ gk,
                      ushort_t* __restrict__ wogT) {
  const size_t i = (size_t)blockIdx.x * 256 + threadIdx.x;
  const size_t c = i * 8;
  const int j0 = (int)(c & (DM - 1));
  const int b = (int)(c >> 20);
  u16x8 wv = *(const u16x8*)(woT + (c & ((1u << 20) - 1)));
  const float4 g0 = *(const float4*)(gk + b * DM + j0);
  const float4 g1 = *(const float4*)(gk + b * DM + j0 + 4);
  float g[8] = {g0.x, g0.y, g0.z, g0.w, g1.x, g1.y, g1.z, g1.w};
  u16x8 o;
#pragma unroll
  for (int j = 0; j < 8; ++j) o[j] = f2bf(bf2f(wv[j]) * g[j]);
  *(u16x8*)(wogT + i * 8) = o;
}

// K6: qbias[n] = sum_j bq[j]*wo[j,n];  vbias[b][n] = sum_j bv[j]*gk[b][j]*wo[j,n]
__global__ void k_bias(const float* __restrict__ wo, const float* __restrict__ bq,
                       const float* __restrict__ bv, const float* __restrict__ gk,
                       float* __restrict__ qbias, float* __restrict__ vbias) {
  const int n = blockIdx.x * 256 + threadIdx.x;
  const int k0 = blockIdx.y * 32;
  float aq = 0.f, av[4] = {0.f, 0.f, 0.f, 0.f};
  for (int kk = 0; kk < 32; ++kk) {
    const float w = wo[(size_t)(k0 + kk) * DM + n];
    aq += bq[k0 + kk] * w;
    const float bw = bv[k0 + kk] * w;
#pragma unroll
    for (int b = 0; b < 4; ++b) av[b] += bw * gk[b * DM + k0 + kk];
  }
  atomicAdd(&qbias[n], aq);
#pragma unroll
  for (int b = 0; b < 4; ++b) atomicAdd(&vbias[b * DM + n], av[b]);
}

// ---------------------------------------------------------------------------
// K7: small weight GEMMs, 128x128 tile, BK=32, 3-buf 2-deep, swizzled. (unchanged)
__global__ void k_small(const ushort_t* __restrict__ woT, const ushort_t* __restrict__ wogT,
                        const ushort_t* __restrict__ wqB, const ushort_t* __restrict__ wvB,
                        ushort_t* __restrict__ WqoT, ushort_t* __restrict__ WvbT) {
  __shared__ __align__(16) ushort_t lsA[3][128 * 32];
  __shared__ __align__(16) ushort_t lsB[3][128 * 32];
  const int z = blockIdx.z;
  const ushort_t* A  = z == 0 ? woT : wogT + (size_t)(z - 1) * (DM * DM);
  const ushort_t* Bt = z == 0 ? wqB : wvB;
  ushort_t* Out      = z == 0 ? WqoT : WvbT + (size_t)(z - 1) * (DM * DM);

  const int tid = threadIdx.x;
  const int w = tid >> 6, lane = tid & 63;
  const int m0 = blockIdx.x * 128, n0 = blockIdx.y * 128;
  const int wr = w >> 1, wc = w & 1;
  const int c0 = w * 2, c1 = c0 + 1;
  const int e0 = c0 * 64 + lane, e1 = c1 * 64 + lane;
  const ushort_t* gA0 = A + src_off(m0, e0);
  const ushort_t* gA1 = A + src_off(m0, e1);
  const ushort_t* gB0 = Bt + src_off(n0, e0);
  const ushort_t* gB1 = Bt + src_off(n0, e1);

  int aoff[4], boff[4];
#pragma unroll
  for (int i = 0; i < 4; ++i) {
    const int ra = wr * 64 + i * 16 + (lane & 15);
    aoff[i] = ra * 32 + (((lane >> 4) ^ ((ra >> 1) & 3)) * 8);
    const int rb = wc * 64 + i * 16 + (lane & 15);
    boff[i] = rb * 32 + (((lane >> 4) ^ ((rb >> 1) & 3)) * 8);
  }

  f32x4 acc[4][4];
#pragma unroll
  for (int i = 0; i < 4; ++i)
#pragma unroll
    for (int j = 0; j < 4; ++j) acc[i][j] = (f32x4){0.f, 0.f, 0.f, 0.f};

  auto STAGE = [&](int tt, int buf) {
    const int o = tt * 32;
    GLL(gA0 + o, &lsA[buf][c0 * 512]);
    GLL(gA1 + o, &lsA[buf][c1 * 512]);
    GLL(gB0 + o, &lsB[buf][c0 * 512]);
    GLL(gB1 + o, &lsB[buf][c1 * 512]);
  };

  STAGE(0, 0);
  STAGE(1, 1);
#pragma unroll 1
  for (int t = 0; t < 32; ++t) {
    if (t < 31) { asm volatile("s_waitcnt vmcnt(4)" ::: "memory"); }
    else        { asm volatile("s_waitcnt vmcnt(0)" ::: "memory"); }
    __builtin_amdgcn_s_barrier();
    if (t + 2 < 32) STAGE(t + 2, (t + 2) % 3);
    const int cur = t % 3;
    bf16x8 av[4], bv[4];
#pragma unroll
    for (int i = 0; i < 4; ++i) av[i] = *(const bf16x8*)(&lsA[cur][aoff[i]]);
#pragma unroll
    for (int j = 0; j < 4; ++j) bv[j] = *(const bf16x8*)(&lsB[cur][boff[j]]);
#pragma unroll
    for (int i = 0; i < 4; ++i)
#pragma unroll
      for (int j = 0; j < 4; ++j)
        acc[i][j] = __builtin_amdgcn_mfma_f32_16x16x32_bf16(av[i], bv[j], acc[i][j], 0, 0, 0);
  }

  const int lr = (lane >> 4) * 4, lc = lane & 15;
  const int rbase = m0 + wr * 64, cbase = n0 + wc * 64;
#pragma unroll
  for (int j = 0; j < 4; ++j) {
    const int col = cbase + j * 16 + lc;
#pragma unroll
    for (int i = 0; i < 4; ++i)
#pragma unroll
      for (int t = 0; t < 4; ++t)
        Out[(size_t)(rbase + i * 16 + lr + t) * DM + col] = f2bf(acc[i][j][t]);
  }
}

// ---------------------------------------------------------------------------
// K8: big GEMM, BM=256 BN=128 BK=64, 8 waves (2M x 4N: per-wave 128x32),
// 3-buf LDS, phase-split schedule (R10 WIN: 53->46us). Unchanged.
__global__ __launch_bounds__(512, 1)
void k_big(const ushort_t* __restrict__ qb, const ushort_t* __restrict__ vb,
           const ushort_t* __restrict__ WqoT, const ushort_t* __restrict__ WvbT,
           const float* __restrict__ gqw, const float* __restrict__ qbias,
           const float* __restrict__ vbias, const float* __restrict__ bo,
           float* __restrict__ Out) {
  __shared__ __align__(16) ushort_t lsA[3][256 * 64];  // 3 x 32 KB
  __shared__ __align__(16) ushort_t lsB[3][128 * 64];  // 3 x 16 KB
  const int tid = threadIdx.x;
  const int w = tid >> 6, lane = tid & 63;
  const int m0 = blockIdx.x * 256, n0 = blockIdx.y * 128;
  const int b = m0 >> 11;
  const int wr = w >> 2, wc = w & 3;  // 2x4 wave grid, per-wave 128x32 out

  const int subrow = lane >> 3;
  const int srcslot = (lane & 7) ^ subrow;
  size_t offA[4], offB[2];
#pragma unroll
  for (int p = 0; p < 4; ++p) {
    const int row = (4 * w + p) * 8 + subrow;           // 0..255
    offA[p] = (size_t)(m0 + row) * DM + srcslot * 8;
  }
#pragma unroll
  for (int p = 0; p < 2; ++p) {
    const int row = (2 * w + p) * 8 + subrow;           // 0..127
    offB[p] = (size_t)(n0 + row) * DM + srcslot * 8;
  }
  const ushort_t* Bv = WvbT + (size_t)b * (DM * DM);

  const int g = lane >> 4, l7 = lane & 7, l15 = lane & 15;
  int aoff[2][8], boff[2][2];
#pragma unroll
  for (int kh = 0; kh < 2; ++kh) {
#pragma unroll
    for (int i = 0; i < 8; ++i) {
      const int ra = wr * 128 + i * 16 + l15;
      aoff[kh][i] = ra * 64 + (((kh * 4 + g) ^ l7) * 8);
    }
#pragma unroll
    for (int j = 0; j < 2; ++j) {
      const int rb = wc * 32 + j * 16 + l15;
      boff[kh][j] = rb * 64 + (((kh * 4 + g) ^ l7) * 8);
    }
  }

  f32x4 acc[8][2];
#pragma unroll
  for (int i = 0; i < 8; ++i)
#pragma unroll
    for (int j = 0; j < 2; ++j) acc[i][j] = (f32x4){0.f, 0.f, 0.f, 0.f};

  auto SRC = [&](int tt, const ushort_t*& Ab, const ushort_t*& Bb, int& k0) {
    if (tt < 16) { Ab = qb; Bb = WqoT; k0 = tt * 64; }
    else         { Ab = vb; Bb = Bv;   k0 = (tt - 16) * 64; }
  };
  auto STAGE_H0 = [&](int tt, int buf) {   // 3 GLL: A chunks p=0,1 + B chunk p=0
    const ushort_t *Ab, *Bb; int k0; SRC(tt, Ab, Bb, k0);
    GLL(Ab + offA[0] + k0, &lsA[buf][(4 * w + 0) * 512]);
    GLL(Ab + offA[1] + k0, &lsA[buf][(4 * w + 1) * 512]);
    GLL(Bb + offB[0] + k0, &lsB[buf][(2 * w + 0) * 512]);
  };
  auto STAGE_H1 = [&](int tt, int buf) {   // 3 GLL: A chunks p=2,3 + B chunk p=1
    const ushort_t *Ab, *Bb; int k0; SRC(tt, Ab, Bb, k0);
    GLL(Ab + offA[2] + k0, &lsA[buf][(4 * w + 2) * 512]);
    GLL(Ab + offA[3] + k0, &lsA[buf][(4 * w + 3) * 512]);
    GLL(Bb + offB[1] + k0, &lsB[buf][(2 * w + 1) * 512]);
  };

  STAGE_H0(0, 0); STAGE_H1(0, 0);
  STAGE_H0(1, 1); STAGE_H1(1, 1);
#pragma unroll 1
  for (int t = 0; t < 32; ++t) {
    const int cur = t % 3, nb = (t + 2) % 3;
    const bool st = (t + 2 < 32);
    if (t < 31) { asm volatile("s_waitcnt vmcnt(6)\n\ts_barrier" ::: "memory"); }
    else        { asm volatile("s_waitcnt vmcnt(0)\n\ts_barrier" ::: "memory"); }
    // ---- phase 0 (khalf 0) ----
    {
      bf16x8 av[8], bv[2];
#pragma unroll
      for (int i = 0; i < 8; ++i) av[i] = *(const bf16x8*)(&lsA[cur][aoff[0][i]]);
#pragma unroll
      for (int j = 0; j < 2; ++j) bv[j] = *(const bf16x8*)(&lsB[cur][boff[0][j]]);
      if (st) STAGE_H0(t + 2, nb);
      __builtin_amdgcn_s_setprio(1);
#pragma unroll
      for (int i = 0; i < 8; ++i)
#pragma unroll
        for (int j = 0; j < 2; ++j)
          acc[i][j] = __builtin_amdgcn_mfma_f32_16x16x32_bf16(av[i], bv[j], acc[i][j], 0, 0, 0);
      __builtin_amdgcn_s_setprio(0);
      asm volatile("s_barrier" ::: "memory");
    }
    // ---- phase 1 (khalf 1) ----
    {
      bf16x8 av[8], bv[2];
#pragma unroll
      for (int i = 0; i < 8; ++i) av[i] = *(const bf16x8*)(&lsA[cur][aoff[1][i]]);
#pragma unroll
      for (int j = 0; j < 2; ++j) bv[j] = *(const bf16x8*)(&lsB[cur][boff[1][j]]);
      if (st) STAGE_H1(t + 2, nb);
      __builtin_amdgcn_s_setprio(1);
#pragma unroll
      for (int i = 0; i < 8; ++i)
#pragma unroll
        for (int j = 0; j < 2; ++j)
          acc[i][j] = __builtin_amdgcn_mfma_f32_16x16x32_bf16(av[i], bv[j], acc[i][j], 0, 0, 0);
      __builtin_amdgcn_s_setprio(0);
      asm volatile("s_barrier" ::: "memory");
    }
  }

  // epilogue: C/D layout col = lane&15, row = (lane>>4)*4 + reg
  const int lr = (lane >> 4) * 4, lc = lane & 15;
  const int rbase = m0 + wr * 128, cbase = n0 + wc * 32;
#pragma unroll
  for (int j = 0; j < 2; ++j) {
    const int col = cbase + j * 16 + lc;
    const float qbn = qbias[col];
    const float cb = vbias[b * DM + col] + bo[col];
#pragma unroll
    for (int i = 0; i < 8; ++i)
#pragma unroll
      for (int r = 0; r < 4; ++r) {
        const int row = rbase + i * 16 + lr + r;
        Out[(size_t)row * DM + col] = acc[i][j][r] + gqw[row & (SEQ - 1)] * qbn + cb;
      }
  }
}

// ---------------------------------------------------------------------------
extern "C" void kernel_launch(void* const* d_in, const int* in_sizes, int n_in,
                              void* d_out, int out_size, void* d_ws, size_t ws_size,
                              hipStream_t stream) {
  // input order: v k q mask wq bq wk bk wv bv gqw gkw wo bo
  const float* v   = (const float*)d_in[0];
  const float* k   = (const float*)d_in[1];
  const float* q   = (const float*)d_in[2];
  const float* wq  = (const float*)d_in[4];
  const float* bq  = (const float*)d_in[5];
  const float* wk  = (const float*)d_in[6];
  const float* bk  = (const float*)d_in[7];
  const float* wv  = (const float*)d_in[8];
  const float* bv  = (const float*)d_in[9];
  const float* gqw = (const float*)d_in[10];
  const float* gkw = (const float*)d_in[11];
  const float* wo  = (const float*)d_in[12];
  const float* bo  = (const float*)d_in[13];
  float* out = (float*)d_out;
  float* wsf = (float*)d_ws;

  // fp32 scratch: [qr kr qacc kacc | G | qbias | vbias | gk]
  float* qr    = wsf + 0;
  float* kr    = wsf + 4096;
  float* qacc  = wsf + 8192;
  float* kacc  = wsf + 12288;
  float* G     = wsf + 16384;   // 2 floats
  float* qbias = wsf + 16640;   // 1024
  float* vbias = wsf + 17664;   // 4096
  float* gk    = wsf + 21760;   // 4096 (fully written by k_gfin)
  // bf16 scratch at byte offset 128 KiB
  ushort_t* b16  = (ushort_t*)((char*)d_ws + (1 << 17));
  ushort_t* qb   = b16;                                 // 16MB gqw-scaled
  ushort_t* vb   = qb + (size_t)M_TOT * DM;             // 16MB
  ushort_t* wqB  = vb + (size_t)M_TOT * DM;             // 2MB
  ushort_t* wvB  = wqB + (size_t)DM * DM;               // 2MB
  ushort_t* woT  = wvB + (size_t)DM * DM;               // 2MB [N][K]
  ushort_t* WqoT = woT + (size_t)DM * DM;               // 2MB
  ushort_t* WvbT = WqoT + (size_t)DM * DM;              // 8MB [4][N][K]
  ushort_t* wogT = (ushort_t*)out;  // 8MB alias in d_out; dead before k_big writes

  hipMemsetAsync(d_ws, 0, 21760 * sizeof(float), stream);

  // weight preps
  k_conv<<<dim3((DM * DM / 8) / 256, 2), 256, 0, stream>>>(wq, wqB, wv, wvB);
  k_trans<<<dim3(32, 32), 256, 0, stream>>>(wo, woT);

  // data reductions + bf16 conversions (vectorized float4/ushort4)
  k_reduce<<<dim3(BATCH, SEQ / 16), 256, 0, stream>>>(q, k, v, gqw, gkw, qr, kr, G, qb, vb);

  // gk
  k_gpart<<<dim3(DM / 256, DM / 32), 256, 0, stream>>>(wq, wk, qr, kr, qacc, kacc);
  k_gfin<<<(BATCH * DM) / 256, 256, 0, stream>>>(qacc, kacc, bq, bk, G, gk);

  // composed-weight preps
  k_wog<<<(BATCH * DM * DM / 8) / 256, 256, 0, stream>>>(woT, gk, wogT);
  k_bias<<<dim3(DM / 256, DM / 32), 256, 0, stream>>>(wo, bq, bv, gk, qbias, vbias);

  // small GEMMs: WqoT, WvbT[0..3]
  k_small<<<dim3(8, 8, 5), 256, 0, stream>>>(woT, wogT, wqB, wvB, WqoT, WvbT);

  // the one big GEMM -> out (plain 2D grid, x-fastest: B-panel sharing)
  k_big<<<dim3(M_TOT / 256, DM / 128), 512, 0, stream>>>(
      qb, vb, WqoT, WvbT, gqw, qbias, vbias, bo, out);
}

// Round 13
// 127.451 us; speedup vs baseline: 1.0628x; 1.0628x over previous
//
#include <hip/hip_runtime.h>

#define DM 1024
#define BATCH 4
#define SEQ 2048
#define M_TOT (BATCH*SEQ)

typedef unsigned short ushort_t;
typedef __bf16 bf16x8 __attribute__((ext_vector_type(8)));
typedef float f32x4 __attribute__((ext_vector_type(4)));
typedef unsigned short u16x4 __attribute__((ext_vector_type(4)));
typedef unsigned short u16x8 __attribute__((ext_vector_type(8)));

__device__ __forceinline__ ushort_t f2bf(float f) {
  unsigned u = __builtin_bit_cast(unsigned, f);
  u = (u + 0x7fffu + ((u >> 16) & 1u)) >> 16;
  return (ushort_t)u;
}
__device__ __forceinline__ float bf2f(ushort_t h) {
  unsigned u = ((unsigned)h) << 16;
  return __builtin_bit_cast(float, u);
}

// async global->LDS, 16B per lane, wave-uniform LDS base + lane*16
#define GLL(gp, lp)                                                            \
  __builtin_amdgcn_global_load_lds(                                            \
      (const __attribute__((address_space(1))) unsigned int*)(const void*)(gp),\
      (__attribute__((address_space(3))) unsigned int*)(void*)(lp), 16, 0, 0)

// 4-slot swizzle for BK=32 kernels (k_small): verified R7, conflicts -> 0.
__device__ __forceinline__ size_t src_off(int row0, int e) {
  return (size_t)(row0 + (e >> 2)) * DM + (((e & 3) ^ ((e >> 3) & 3)) * 8);
}

// ---------------------------------------------------------------------------
// K1 (ATOMIC-FREE): per-block partial sums of gqw*q and gkw*k over 8 rows,
// written as coalesced float4 stores; qb = bf16(gqw*q), vb = bf16(v).
// grid (BATCH, SEQ/8), block 256, thread owns 4 consecutive cols.
__global__ void k_reduce(const float* __restrict__ q, const float* __restrict__ k,
                         const float* __restrict__ v,
                         const float* __restrict__ gqw, const float* __restrict__ gkw,
                         float* __restrict__ pq, float* __restrict__ pk,
                         float* __restrict__ G,
                         ushort_t* __restrict__ qb, ushort_t* __restrict__ vb) {
  const int b = blockIdx.x, sc = blockIdx.y;   // sc: 0..255 (8-row chunks)
  const int d0 = threadIdx.x * 4;
  const int s0 = sc * 8;
  const size_t base = ((size_t)b * SEQ + s0) * DM + d0;
  float aq0 = 0.f, aq1 = 0.f, aq2 = 0.f, aq3 = 0.f;
  float ak0 = 0.f, ak1 = 0.f, ak2 = 0.f, ak3 = 0.f;
  float sgq = 0.f, sgk = 0.f;
#pragma unroll
  for (int i = 0; i < 8; ++i) {
    const float wq_ = gqw[s0 + i], wk_ = gkw[s0 + i];
    const size_t off = base + (size_t)i * DM;
    const float4 qv = *(const float4*)(q + off);
    const float4 kv = *(const float4*)(k + off);
    const float4 vv = *(const float4*)(v + off);
    aq0 += wq_ * qv.x; aq1 += wq_ * qv.y; aq2 += wq_ * qv.z; aq3 += wq_ * qv.w;
    ak0 += wk_ * kv.x; ak1 += wk_ * kv.y; ak2 += wk_ * kv.z; ak3 += wk_ * kv.w;
    u16x4 oq, ov;
    oq[0] = f2bf(wq_ * qv.x); oq[1] = f2bf(wq_ * qv.y);
    oq[2] = f2bf(wq_ * qv.z); oq[3] = f2bf(wq_ * qv.w);
    ov[0] = f2bf(vv.x); ov[1] = f2bf(vv.y); ov[2] = f2bf(vv.z); ov[3] = f2bf(vv.w);
    *(u16x4*)(qb + off) = oq;
    *(u16x4*)(vb + off) = ov;
    sgq += wq_; sgk += wk_;
  }
  const size_t po = ((size_t)(sc * BATCH + b) << 10) + d0;
  *(float4*)(pq + po) = make_float4(aq0, aq1, aq2, aq3);
  *(float4*)(pk + po) = make_float4(ak0, ak1, ak2, ak3);
  if (b == 0 && threadIdx.x == 0) {
    atomicAdd(&G[0], sgq);
    atomicAdd(&G[1], sgk);
  }
}

// K1b: fold 256 partial slots into qr/kr. grid (4, 4, 8): b, 256-col chunk,
// 32-slot group. Coalesced (lanes sweep d). 32K atomics total.
__global__ void k_rsum(const float* __restrict__ pq, const float* __restrict__ pk,
                       float* __restrict__ qr, float* __restrict__ kr) {
  const int b = blockIdx.x;
  const int d = blockIdx.y * 256 + threadIdx.x;
  const int sg = blockIdx.z;
  float aq = 0.f, ak = 0.f;
#pragma unroll 4
  for (int s = sg * 32; s < sg * 32 + 32; ++s) {
    const size_t po = ((size_t)(s * BATCH + b) << 10) + d;
    aq += pq[po];
    ak += pk[po];
  }
  atomicAdd(&qr[b * DM + d], aq);
  atomicAdd(&kr[b * DM + d], ak);
}

// K2a: partial GEMV over K-chunks
__global__ void k_gpart(const float* __restrict__ wq, const float* __restrict__ wk,
                        const float* __restrict__ qr, const float* __restrict__ kr,
                        float* __restrict__ qacc, float* __restrict__ kacc) {
  const int d = blockIdx.x * 256 + threadIdx.x;
  const int k0 = blockIdx.y * 32;
  __shared__ float sq[4][32], sk[4][32];
  if (threadIdx.x < 128) {
    const int b = threadIdx.x >> 5, kk = threadIdx.x & 31;
    sq[b][kk] = qr[b * DM + k0 + kk];
    sk[b][kk] = kr[b * DM + k0 + kk];
  }
  __syncthreads();
  float aq[4] = {0.f, 0.f, 0.f, 0.f}, ak[4] = {0.f, 0.f, 0.f, 0.f};
#pragma unroll 8
  for (int kk = 0; kk < 32; ++kk) {
    const float wqv = wq[(size_t)(k0 + kk) * DM + d];
    const float wkv = wk[(size_t)(k0 + kk) * DM + d];
#pragma unroll
    for (int b = 0; b < 4; ++b) {
      aq[b] += sq[b][kk] * wqv;
      ak[b] += sk[b][kk] * wkv;
    }
  }
#pragma unroll
  for (int b = 0; b < 4; ++b) {
    atomicAdd(&qacc[b * DM + d], aq[b]);
    atomicAdd(&kacc[b * DM + d], ak[b]);
  }
}

// K2b: gk[b,d] = (qacc + bq[d]*G0) * (kacc + bk[d]*G1)
__global__ void k_gfin(const float* __restrict__ qacc, const float* __restrict__ kacc,
                       const float* __restrict__ bq, const float* __restrict__ bk,
                       const float* __restrict__ G, float* __restrict__ gk) {
  const int i = blockIdx.x * 256 + threadIdx.x;
  const int d = i & (DM - 1);
  const float gqv = qacc[i] + bq[d] * G[0];
  const float gkr = kacc[i] + bk[d] * G[1];
  gk[i] = gqv * gkr;
}

// K3: fp32 -> bf16 row-major convert (y=0: wq->wqB, y=1: wv->wvB)
__global__ void k_conv(const float* __restrict__ x0, ushort_t* __restrict__ y0,
                       const float* __restrict__ x1, ushort_t* __restrict__ y1) {
  const float* x = blockIdx.y ? x1 : x0;
  ushort_t* y = blockIdx.y ? y1 : y0;
  size_t i = (size_t)blockIdx.x * 256 + threadIdx.x;
  const float4* p = (const float4*)x + i * 2;
  float4 a = p[0], b = p[1];
  u16x8 o;
  o[0] = f2bf(a.x); o[1] = f2bf(a.y); o[2] = f2bf(a.z); o[3] = f2bf(a.w);
  o[4] = f2bf(b.x); o[5] = f2bf(b.y); o[6] = f2bf(b.z); o[7] = f2bf(b.w);
  *(u16x8*)(y + i * 8) = o;
}

// K4: transpose-convert wo [K][N] fp32 -> woT [N][K] bf16
__global__ void k_trans(const float* __restrict__ W, ushort_t* __restrict__ T) {
  __shared__ float ls[32][33];
  const int bi = blockIdx.x, bj = blockIdx.y;
#pragma unroll
  for (int p = 0; p < 4; ++p) {
    int e = threadIdx.x + p * 256;
    int r = e >> 5, c = e & 31;
    ls[r][c] = W[(size_t)(bi * 32 + r) * DM + bj * 32 + c];
  }
  __syncthreads();
#pragma unroll
  for (int p = 0; p < 4; ++p) {
    int e = threadIdx.x + p * 256;
    int r = e >> 5, c = e & 31;
    T[(size_t)(bj * 32 + r) * DM + bi * 32 + c] = f2bf(ls[c][r]);
  }
}

// K5: wogT[b][n][j] = woT[n][j] * gk[b][j]
__global__ void k_wog(const ushort_t* __restrict__ woT, const float* __restrict__ gk,
                      ushort_t* __restrict__ wogT) {
  const size_t i = (size_t)blockIdx.x * 256 + threadIdx.x;
  const size_t c = i * 8;
  const int j0 = (int)(c & (DM - 1));
  const int b = (int)(c >> 20);
  u16x8 wv = *(const u16x8*)(woT + (c & ((1u << 20) - 1)));
  const float4 g0 = *(const float4*)(gk + b * DM + j0);
  const float4 g1 = *(const float4*)(gk + b * DM + j0 + 4);
  float g[8] = {g0.x, g0.y, g0.z, g0.w, g1.x, g1.y, g1.z, g1.w};
  u16x8 o;
#pragma unroll
  for (int j = 0; j < 8; ++j) o[j] = f2bf(bf2f(wv[j]) * g[j]);
  *(u16x8*)(wogT + i * 8) = o;
}

// K6: qbias[n] = sum_j bq[j]*wo[j,n];  vbias[b][n] = sum_j bv[j]*gk[b][j]*wo[j,n]
__global__ void k_bias(const float* __restrict__ wo, const float* __restrict__ bq,
                       const float* __restrict__ bv, const float* __restrict__ gk,
                       float* __restrict__ qbias, float* __restrict__ vbias) {
  const int n = blockIdx.x * 256 + threadIdx.x;
  const int k0 = blockIdx.y * 32;
  float aq = 0.f, av[4] = {0.f, 0.f, 0.f, 0.f};
  for (int kk = 0; kk < 32; ++kk) {
    const float w = wo[(size_t)(k0 + kk) * DM + n];
    aq += bq[k0 + kk] * w;
    const float bw = bv[k0 + kk] * w;
#pragma unroll
    for (int b = 0; b < 4; ++b) av[b] += bw * gk[b * DM + k0 + kk];
  }
  atomicAdd(&qbias[n], aq);
#pragma unroll
  for (int b = 0; b < 4; ++b) atomicAdd(&vbias[b * DM + n], av[b]);
}

// ---------------------------------------------------------------------------
// K7: small weight GEMMs, 128x128 tile, BK=32, 3-buf 2-deep, swizzled. (unchanged)
__global__ void k_small(const ushort_t* __restrict__ woT, const ushort_t* __restrict__ wogT,
                        const ushort_t* __restrict__ wqB, const ushort_t* __restrict__ wvB,
                        ushort_t* __restrict__ WqoT, ushort_t* __restrict__ WvbT) {
  __shared__ __align__(16) ushort_t lsA[3][128 * 32];
  __shared__ __align__(16) ushort_t lsB[3][128 * 32];
  const int z = blockIdx.z;
  const ushort_t* A  = z == 0 ? woT : wogT + (size_t)(z - 1) * (DM * DM);
  const ushort_t* Bt = z == 0 ? wqB : wvB;
  ushort_t* Out      = z == 0 ? WqoT : WvbT + (size_t)(z - 1) * (DM * DM);

  const int tid = threadIdx.x;
  const int w = tid >> 6, lane = tid & 63;
  const int m0 = blockIdx.x * 128, n0 = blockIdx.y * 128;
  const int wr = w >> 1, wc = w & 1;
  const int c0 = w * 2, c1 = c0 + 1;
  const int e0 = c0 * 64 + lane, e1 = c1 * 64 + lane;
  const ushort_t* gA0 = A + src_off(m0, e0);
  const ushort_t* gA1 = A + src_off(m0, e1);
  const ushort_t* gB0 = Bt + src_off(n0, e0);
  const ushort_t* gB1 = Bt + src_off(n0, e1);

  int aoff[4], boff[4];
#pragma unroll
  for (int i = 0; i < 4; ++i) {
    const int ra = wr * 64 + i * 16 + (lane & 15);
    aoff[i] = ra * 32 + (((lane >> 4) ^ ((ra >> 1) & 3)) * 8);
    const int rb = wc * 64 + i * 16 + (lane & 15);
    boff[i] = rb * 32 + (((lane >> 4) ^ ((rb >> 1) & 3)) * 8);
  }

  f32x4 acc[4][4];
#pragma unroll
  for (int i = 0; i < 4; ++i)
#pragma unroll
    for (int j = 0; j < 4; ++j) acc[i][j] = (f32x4){0.f, 0.f, 0.f, 0.f};

  auto STAGE = [&](int tt, int buf) {
    const int o = tt * 32;
    GLL(gA0 + o, &lsA[buf][c0 * 512]);
    GLL(gA1 + o, &lsA[buf][c1 * 512]);
    GLL(gB0 + o, &lsB[buf][c0 * 512]);
    GLL(gB1 + o, &lsB[buf][c1 * 512]);
  };

  STAGE(0, 0);
  STAGE(1, 1);
#pragma unroll 1
  for (int t = 0; t < 32; ++t) {
    if (t < 31) { asm volatile("s_waitcnt vmcnt(4)" ::: "memory"); }
    else        { asm volatile("s_waitcnt vmcnt(0)" ::: "memory"); }
    __builtin_amdgcn_s_barrier();
    if (t + 2 < 32) STAGE(t + 2, (t + 2) % 3);
    const int cur = t % 3;
    bf16x8 av[4], bv[4];
#pragma unroll
    for (int i = 0; i < 4; ++i) av[i] = *(const bf16x8*)(&lsA[cur][aoff[i]]);
#pragma unroll
    for (int j = 0; j < 4; ++j) bv[j] = *(const bf16x8*)(&lsB[cur][boff[j]]);
#pragma unroll
    for (int i = 0; i < 4; ++i)
#pragma unroll
      for (int j = 0; j < 4; ++j)
        acc[i][j] = __builtin_amdgcn_mfma_f32_16x16x32_bf16(av[i], bv[j], acc[i][j], 0, 0, 0);
  }

  const int lr = (lane >> 4) * 4, lc = lane & 15;
  const int rbase = m0 + wr * 64, cbase = n0 + wc * 64;
#pragma unroll
  for (int j = 0; j < 4; ++j) {
    const int col = cbase + j * 16 + lc;
#pragma unroll
    for (int i = 0; i < 4; ++i)
#pragma unroll
      for (int t = 0; t < 4; ++t)
        Out[(size_t)(rbase + i * 16 + lr + t) * DM + col] = f2bf(acc[i][j][t]);
  }
}

// ---------------------------------------------------------------------------
// K8: big GEMM, BM=256 BN=128 BK=64, 8 waves (2M x 4N: per-wave 128x32),
// 3-buf LDS, phase-split schedule (R10 WIN: 53->46us). Unchanged.
__global__ __launch_bounds__(512, 1)
void k_big(const ushort_t* __restrict__ qb, const ushort_t* __restrict__ vb,
           const ushort_t* __restrict__ WqoT, const ushort_t* __restrict__ WvbT,
           const float* __restrict__ gqw, const float* __restrict__ qbias,
           const float* __restrict__ vbias, const float* __restrict__ bo,
           float* __restrict__ Out) {
  __shared__ __align__(16) ushort_t lsA[3][256 * 64];  // 3 x 32 KB
  __shared__ __align__(16) ushort_t lsB[3][128 * 64];  // 3 x 16 KB
  const int tid = threadIdx.x;
  const int w = tid >> 6, lane = tid & 63;
  const int m0 = blockIdx.x * 256, n0 = blockIdx.y * 128;
  const int b = m0 >> 11;
  const int wr = w >> 2, wc = w & 3;  // 2x4 wave grid, per-wave 128x32 out

  const int subrow = lane >> 3;
  const int srcslot = (lane & 7) ^ subrow;
  size_t offA[4], offB[2];
#pragma unroll
  for (int p = 0; p < 4; ++p) {
    const int row = (4 * w + p) * 8 + subrow;           // 0..255
    offA[p] = (size_t)(m0 + row) * DM + srcslot * 8;
  }
#pragma unroll
  for (int p = 0; p < 2; ++p) {
    const int row = (2 * w + p) * 8 + subrow;           // 0..127
    offB[p] = (size_t)(n0 + row) * DM + srcslot * 8;
  }
  const ushort_t* Bv = WvbT + (size_t)b * (DM * DM);

  const int g = lane >> 4, l7 = lane & 7, l15 = lane & 15;
  int aoff[2][8], boff[2][2];
#pragma unroll
  for (int kh = 0; kh < 2; ++kh) {
#pragma unroll
    for (int i = 0; i < 8; ++i) {
      const int ra = wr * 128 + i * 16 + l15;
      aoff[kh][i] = ra * 64 + (((kh * 4 + g) ^ l7) * 8);
    }
#pragma unroll
    for (int j = 0; j < 2; ++j) {
      const int rb = wc * 32 + j * 16 + l15;
      boff[kh][j] = rb * 64 + (((kh * 4 + g) ^ l7) * 8);
    }
  }

  f32x4 acc[8][2];
#pragma unroll
  for (int i = 0; i < 8; ++i)
#pragma unroll
    for (int j = 0; j < 2; ++j) acc[i][j] = (f32x4){0.f, 0.f, 0.f, 0.f};

  auto SRC = [&](int tt, const ushort_t*& Ab, const ushort_t*& Bb, int& k0) {
    if (tt < 16) { Ab = qb; Bb = WqoT; k0 = tt * 64; }
    else         { Ab = vb; Bb = Bv;   k0 = (tt - 16) * 64; }
  };
  auto STAGE_H0 = [&](int tt, int buf) {   // 3 GLL: A chunks p=0,1 + B chunk p=0
    const ushort_t *Ab, *Bb; int k0; SRC(tt, Ab, Bb, k0);
    GLL(Ab + offA[0] + k0, &lsA[buf][(4 * w + 0) * 512]);
    GLL(Ab + offA[1] + k0, &lsA[buf][(4 * w + 1) * 512]);
    GLL(Bb + offB[0] + k0, &lsB[buf][(2 * w + 0) * 512]);
  };
  auto STAGE_H1 = [&](int tt, int buf) {   // 3 GLL: A chunks p=2,3 + B chunk p=1
    const ushort_t *Ab, *Bb; int k0; SRC(tt, Ab, Bb, k0);
    GLL(Ab + offA[2] + k0, &lsA[buf][(4 * w + 2) * 512]);
    GLL(Ab + offA[3] + k0, &lsA[buf][(4 * w + 3) * 512]);
    GLL(Bb + offB[1] + k0, &lsB[buf][(2 * w + 1) * 512]);
  };

  STAGE_H0(0, 0); STAGE_H1(0, 0);
  STAGE_H0(1, 1); STAGE_H1(1, 1);
#pragma unroll 1
  for (int t = 0; t < 32; ++t) {
    const int cur = t % 3, nb = (t + 2) % 3;
    const bool st = (t + 2 < 32);
    if (t < 31) { asm volatile("s_waitcnt vmcnt(6)\n\ts_barrier" ::: "memory"); }
    else        { asm volatile("s_waitcnt vmcnt(0)\n\ts_barrier" ::: "memory"); }
    // ---- phase 0 (khalf 0) ----
    {
      bf16x8 av[8], bv[2];
#pragma unroll
      for (int i = 0; i < 8; ++i) av[i] = *(const bf16x8*)(&lsA[cur][aoff[0][i]]);
#pragma unroll
      for (int j = 0; j < 2; ++j) bv[j] = *(const bf16x8*)(&lsB[cur][boff[0][j]]);
      if (st) STAGE_H0(t + 2, nb);
      __builtin_amdgcn_s_setprio(1);
#pragma unroll
      for (int i = 0; i < 8; ++i)
#pragma unroll
        for (int j = 0; j < 2; ++j)
          acc[i][j] = __builtin_amdgcn_mfma_f32_16x16x32_bf16(av[i], bv[j], acc[i][j], 0, 0, 0);
      __builtin_amdgcn_s_setprio(0);
      asm volatile("s_barrier" ::: "memory");
    }
    // ---- phase 1 (khalf 1) ----
    {
      bf16x8 av[8], bv[2];
#pragma unroll
      for (int i = 0; i < 8; ++i) av[i] = *(const bf16x8*)(&lsA[cur][aoff[1][i]]);
#pragma unroll
      for (int j = 0; j < 2; ++j) bv[j] = *(const bf16x8*)(&lsB[cur][boff[1][j]]);
      if (st) STAGE_H1(t + 2, nb);
      __builtin_amdgcn_s_setprio(1);
#pragma unroll
      for (int i = 0; i < 8; ++i)
#pragma unroll
        for (int j = 0; j < 2; ++j)
          acc[i][j] = __builtin_amdgcn_mfma_f32_16x16x32_bf16(av[i], bv[j], acc[i][j], 0, 0, 0);
      __builtin_amdgcn_s_setprio(0);
      asm volatile("s_barrier" ::: "memory");
    }
  }

  // epilogue: C/D layout col = lane&15, row = (lane>>4)*4 + reg
  const int lr = (lane >> 4) * 4, lc = lane & 15;
  const int rbase = m0 + wr * 128, cbase = n0 + wc * 32;
#pragma unroll
  for (int j = 0; j < 2; ++j) {
    const int col = cbase + j * 16 + lc;
    const float qbn = qbias[col];
    const float cb = vbias[b * DM + col] + bo[col];
#pragma unroll
    for (int i = 0; i < 8; ++i)
#pragma unroll
      for (int r = 0; r < 4; ++r) {
        const int row = rbase + i * 16 + lr + r;
        Out[(size_t)row * DM + col] = acc[i][j][r] + gqw[row & (SEQ - 1)] * qbn + cb;
      }
  }
}

// ---------------------------------------------------------------------------
extern "C" void kernel_launch(void* const* d_in, const int* in_sizes, int n_in,
                              void* d_out, int out_size, void* d_ws, size_t ws_size,
                              hipStream_t stream) {
  // input order: v k q mask wq bq wk bk wv bv gqw gkw wo bo
  const float* v   = (const float*)d_in[0];
  const float* k   = (const float*)d_in[1];
  const float* q   = (const float*)d_in[2];
  const float* wq  = (const float*)d_in[4];
  const float* bq  = (const float*)d_in[5];
  const float* wk  = (const float*)d_in[6];
  const float* bk  = (const float*)d_in[7];
  const float* wv  = (const float*)d_in[8];
  const float* bv  = (const float*)d_in[9];
  const float* gqw = (const float*)d_in[10];
  const float* gkw = (const float*)d_in[11];
  const float* wo  = (const float*)d_in[12];
  const float* bo  = (const float*)d_in[13];
  float* out = (float*)d_out;
  float* wsf = (float*)d_ws;

  // fp32 scratch: [qr kr qacc kacc | G | qbias | vbias | gk]
  float* qr    = wsf + 0;
  float* kr    = wsf + 4096;
  float* qacc  = wsf + 8192;
  float* kacc  = wsf + 12288;
  float* G     = wsf + 16384;   // 2 floats
  float* qbias = wsf + 16640;   // 1024
  float* vbias = wsf + 17664;   // 4096
  float* gk    = wsf + 21760;   // 4096 (fully written by k_gfin)
  // bf16 scratch at byte offset 128 KiB
  ushort_t* b16  = (ushort_t*)((char*)d_ws + (1 << 17));
  ushort_t* qb   = b16;                                 // 16MB gqw-scaled
  ushort_t* vb   = qb + (size_t)M_TOT * DM;             // 16MB
  ushort_t* wqB  = vb + (size_t)M_TOT * DM;             // 2MB
  ushort_t* wvB  = wqB + (size_t)DM * DM;               // 2MB
  ushort_t* woT  = wvB + (size_t)DM * DM;               // 2MB [N][K]
  ushort_t* WqoT = woT + (size_t)DM * DM;               // 2MB
  ushort_t* WvbT = WqoT + (size_t)DM * DM;              // 8MB [4][N][K]
  // dead d_out space hosts transient buffers (all consumed before k_big writes):
  ushort_t* wogT = (ushort_t*)out;       // [0, 8MB)
  float* pq = out + (1 << 22);           // [16, 20MB): 256 slots x 4 x 1024 f32
  float* pk = pq + (1 << 20);            // [20, 24MB)

  hipMemsetAsync(d_ws, 0, 21760 * sizeof(float), stream);

  // weight preps
  k_conv<<<dim3((DM * DM / 8) / 256, 2), 256, 0, stream>>>(wq, wqB, wv, wvB);
  k_trans<<<dim3(32, 32), 256, 0, stream>>>(wo, woT);

  // data reductions + bf16 conversions (atomic-free partials)
  k_reduce<<<dim3(BATCH, SEQ / 8), 256, 0, stream>>>(q, k, v, gqw, gkw, pq, pk, G, qb, vb);
  k_rsum<<<dim3(BATCH, DM / 256, 8), 256, 0, stream>>>(pq, pk, qr, kr);

  // gk
  k_gpart<<<dim3(DM / 256, DM / 32), 256, 0, stream>>>(wq, wk, qr, kr, qacc, kacc);
  k_gfin<<<(BATCH * DM) / 256, 256, 0, stream>>>(qacc, kacc, bq, bk, G, gk);

  // composed-weight preps
  k_wog<<<(BATCH * DM * DM / 8) / 256, 256, 0, stream>>>(woT, gk, wogT);
  k_bias<<<dim3(DM / 256, DM / 32), 256, 0, stream>>>(wo, bq, bv, gk, qbias, vbias);

  // small GEMMs: WqoT, WvbT[0..3]
  k_small<<<dim3(8, 8, 5), 256, 0, stream>>>(woT, wogT, wqB, wvB, WqoT, WvbT);

  // the one big GEMM -> out (plain 2D grid, x-fastest: B-panel sharing)
  k_big<<<dim3(M_TOT / 256, DM / 128), 512, 0, stream>>>(
      qb, vb, WqoT, WvbT, gqw, qbias, vbias, bo, out);
}

// Round 14
// 123.128 us; speedup vs baseline: 1.1001x; 1.0351x over previous
//
#include <hip/hip_runtime.h>

#define DM 1024
#define BATCH 4
#define SEQ 2048
#define M_TOT (BATCH*SEQ)

typedef unsigned short ushort_t;
typedef __bf16 bf16x8 __attribute__((ext_vector_type(8)));
typedef float f32x4 __attribute__((ext_vector_type(4)));
typedef unsigned short u16x4 __attribute__((ext_vector_type(4)));
typedef unsigned short u16x8 __attribute__((ext_vector_type(8)));

__device__ __forceinline__ ushort_t f2bf(float f) {
  unsigned u = __builtin_bit_cast(unsigned, f);
  u = (u + 0x7fffu + ((u >> 16) & 1u)) >> 16;
  return (ushort_t)u;
}
__device__ __forceinline__ float bf2f(ushort_t h) {
  unsigned u = ((unsigned)h) << 16;
  return __builtin_bit_cast(float, u);
}

// async global->LDS, 16B per lane, wave-uniform LDS base + lane*16
#define GLL(gp, lp)                                                            \
  __builtin_amdgcn_global_load_lds(                                            \
      (const __attribute__((address_space(1))) unsigned int*)(const void*)(gp),\
      (__attribute__((address_space(3))) unsigned int*)(void*)(lp), 16, 0, 0)

// ---------------------------------------------------------------------------
// K1 (ATOMIC-FREE, R13-verified): per-block partial sums, coalesced f4 stores.
__global__ void k_reduce(const float* __restrict__ q, const float* __restrict__ k,
                         const float* __restrict__ v,
                         const float* __restrict__ gqw, const float* __restrict__ gkw,
                         float* __restrict__ pq, float* __restrict__ pk,
                         float* __restrict__ G,
                         ushort_t* __restrict__ qb, ushort_t* __restrict__ vb) {
  const int b = blockIdx.x, sc = blockIdx.y;
  const int d0 = threadIdx.x * 4;
  const int s0 = sc * 8;
  const size_t base = ((size_t)b * SEQ + s0) * DM + d0;
  float aq0 = 0.f, aq1 = 0.f, aq2 = 0.f, aq3 = 0.f;
  float ak0 = 0.f, ak1 = 0.f, ak2 = 0.f, ak3 = 0.f;
  float sgq = 0.f, sgk = 0.f;
#pragma unroll
  for (int i = 0; i < 8; ++i) {
    const float wq_ = gqw[s0 + i], wk_ = gkw[s0 + i];
    const size_t off = base + (size_t)i * DM;
    const float4 qv = *(const float4*)(q + off);
    const float4 kv = *(const float4*)(k + off);
    const float4 vv = *(const float4*)(v + off);
    aq0 += wq_ * qv.x; aq1 += wq_ * qv.y; aq2 += wq_ * qv.z; aq3 += wq_ * qv.w;
    ak0 += wk_ * kv.x; ak1 += wk_ * kv.y; ak2 += wk_ * kv.z; ak3 += wk_ * kv.w;
    u16x4 oq, ov;
    oq[0] = f2bf(wq_ * qv.x); oq[1] = f2bf(wq_ * qv.y);
    oq[2] = f2bf(wq_ * qv.z); oq[3] = f2bf(wq_ * qv.w);
    ov[0] = f2bf(vv.x); ov[1] = f2bf(vv.y); ov[2] = f2bf(vv.z); ov[3] = f2bf(vv.w);
    *(u16x4*)(qb + off) = oq;
    *(u16x4*)(vb + off) = ov;
    sgq += wq_; sgk += wk_;
  }
  const size_t po = ((size_t)(sc * BATCH + b) << 10) + d0;
  *(float4*)(pq + po) = make_float4(aq0, aq1, aq2, aq3);
  *(float4*)(pk + po) = make_float4(ak0, ak1, ak2, ak3);
  if (b == 0 && threadIdx.x == 0) {
    atomicAdd(&G[0], sgq);
    atomicAdd(&G[1], sgk);
  }
}

// K1b: fold 256 partial slots into qr/kr.
__global__ void k_rsum(const float* __restrict__ pq, const float* __restrict__ pk,
                       float* __restrict__ qr, float* __restrict__ kr) {
  const int b = blockIdx.x;
  const int d = blockIdx.y * 256 + threadIdx.x;
  const int sg = blockIdx.z;
  float aq = 0.f, ak = 0.f;
#pragma unroll 4
  for (int s = sg * 32; s < sg * 32 + 32; ++s) {
    const size_t po = ((size_t)(s * BATCH + b) << 10) + d;
    aq += pq[po];
    ak += pk[po];
  }
  atomicAdd(&qr[b * DM + d], aq);
  atomicAdd(&kr[b * DM + d], ak);
}

// K2a: partial GEMV over K-chunks
__global__ void k_gpart(const float* __restrict__ wq, const float* __restrict__ wk,
                        const float* __restrict__ qr, const float* __restrict__ kr,
                        float* __restrict__ qacc, float* __restrict__ kacc) {
  const int d = blockIdx.x * 256 + threadIdx.x;
  const int k0 = blockIdx.y * 32;
  __shared__ float sq[4][32], sk[4][32];
  if (threadIdx.x < 128) {
    const int b = threadIdx.x >> 5, kk = threadIdx.x & 31;
    sq[b][kk] = qr[b * DM + k0 + kk];
    sk[b][kk] = kr[b * DM + k0 + kk];
  }
  __syncthreads();
  float aq[4] = {0.f, 0.f, 0.f, 0.f}, ak[4] = {0.f, 0.f, 0.f, 0.f};
#pragma unroll 8
  for (int kk = 0; kk < 32; ++kk) {
    const float wqv = wq[(size_t)(k0 + kk) * DM + d];
    const float wkv = wk[(size_t)(k0 + kk) * DM + d];
#pragma unroll
    for (int b = 0; b < 4; ++b) {
      aq[b] += sq[b][kk] * wqv;
      ak[b] += sk[b][kk] * wkv;
    }
  }
#pragma unroll
  for (int b = 0; b < 4; ++b) {
    atomicAdd(&qacc[b * DM + d], aq[b]);
    atomicAdd(&kacc[b * DM + d], ak[b]);
  }
}

// K2b: gk[b,d] = (qacc + bq[d]*G0) * (kacc + bk[d]*G1)
__global__ void k_gfin(const float* __restrict__ qacc, const float* __restrict__ kacc,
                       const float* __restrict__ bq, const float* __restrict__ bk,
                       const float* __restrict__ G, float* __restrict__ gk) {
  const int i = blockIdx.x * 256 + threadIdx.x;
  const int d = i & (DM - 1);
  const float gqv = qacc[i] + bq[d] * G[0];
  const float gkr = kacc[i] + bk[d] * G[1];
  gk[i] = gqv * gkr;
}

// K3: fp32 -> bf16 row-major convert (y=0: wq->wqB, y=1: wv->wvB)
__global__ void k_conv(const float* __restrict__ x0, ushort_t* __restrict__ y0,
                       const float* __restrict__ x1, ushort_t* __restrict__ y1) {
  const float* x = blockIdx.y ? x1 : x0;
  ushort_t* y = blockIdx.y ? y1 : y0;
  size_t i = (size_t)blockIdx.x * 256 + threadIdx.x;
  const float4* p = (const float4*)x + i * 2;
  float4 a = p[0], b = p[1];
  u16x8 o;
  o[0] = f2bf(a.x); o[1] = f2bf(a.y); o[2] = f2bf(a.z); o[3] = f2bf(a.w);
  o[4] = f2bf(b.x); o[5] = f2bf(b.y); o[6] = f2bf(b.z); o[7] = f2bf(b.w);
  *(u16x8*)(y + i * 8) = o;
}

// K4: transpose-convert wo [K][N] fp32 -> woT [N][K] bf16
__global__ void k_trans(const float* __restrict__ W, ushort_t* __restrict__ T) {
  __shared__ float ls[32][33];
  const int bi = blockIdx.x, bj = blockIdx.y;
#pragma unroll
  for (int p = 0; p < 4; ++p) {
    int e = threadIdx.x + p * 256;
    int r = e >> 5, c = e & 31;
    ls[r][c] = W[(size_t)(bi * 32 + r) * DM + bj * 32 + c];
  }
  __syncthreads();
#pragma unroll
  for (int p = 0; p < 4; ++p) {
    int e = threadIdx.x + p * 256;
    int r = e >> 5, c = e & 31;
    T[(size_t)(bj * 32 + r) * DM + bi * 32 + c] = f2bf(ls[c][r]);
  }
}

// K5: wogT[b][n][j] = woT[n][j] * gk[b][j]
__global__ void k_wog(const ushort_t* __restrict__ woT, const float* __restrict__ gk,
                      ushort_t* __restrict__ wogT) {
  const size_t i = (size_t)blockIdx.x * 256 + threadIdx.x;
  const size_t c = i * 8;
  const int j0 = (int)(c & (DM - 1));
  const int b = (int)(c >> 20);
  u16x8 wv = *(const u16x8*)(woT + (c & ((1u << 20) - 1)));
  const float4 g0 = *(const float4*)(gk + b * DM + j0);
  const float4 g1 = *(const float4*)(gk + b * DM + j0 + 4);
  float g[8] = {g0.x, g0.y, g0.z, g0.w, g1.x, g1.y, g1.z, g1.w};
  u16x8 o;
#pragma unroll
  for (int j = 0; j < 8; ++j) o[j] = f2bf(bf2f(wv[j]) * g[j]);
  *(u16x8*)(wogT + i * 8) = o;
}

// K6: qbias[n] = sum_j bq[j]*wo[j,n];  vbias[b][n] = sum_j bv[j]*gk[b][j]*wo[j,n]
__global__ void k_bias(const float* __restrict__ wo, const float* __restrict__ bq,
                       const float* __restrict__ bv, const float* __restrict__ gk,
                       float* __restrict__ qbias, float* __restrict__ vbias) {
  const int n = blockIdx.x * 256 + threadIdx.x;
  const int k0 = blockIdx.y * 32;
  float aq = 0.f, av[4] = {0.f, 0.f, 0.f, 0.f};
  for (int kk = 0; kk < 32; ++kk) {
    const float w = wo[(size_t)(k0 + kk) * DM + n];
    aq += bq[k0 + kk] * w;
    const float bw = bv[k0 + kk] * w;
#pragma unroll
    for (int b = 0; b < 4; ++b) av[b] += bw * gk[b * DM + k0 + kk];
  }
  atomicAdd(&qbias[n], aq);
#pragma unroll
  for (int b = 0; b < 4; ++b) atomicAdd(&vbias[b * DM + n], av[b]);
}

// ---------------------------------------------------------------------------
// K_PIPE: read-ahead pipelined GEMM. BM=256 BN=128 BK=64, 8 waves (2Mx4N,
// wave-tile 128x32), 3-buf LDS (144KB). Per K-tile: ONE vmcnt+barrier; ds_read
// of phase p+1 issued BEFORE MFMA of phase p (register double-buffer avA/avB)
// so barrier-wait + MFMA absorb LDS latency (m201 rhythm).
// MODE 0 (NT=32): K_eff=2048, tiles 0..15 qb x WqoT, 16..31 vb x WvbT[b];
//                 f32 epilogue with gqw*qbias + vbias + bo. Grid (32,8).
// MODE 1 (NT=16): weight GEMMs, z=0: woT x wqB -> WqoT; z>0: wogT[z-1] x wvB
//                 -> WvbT[z-1] (Out = base + z*DM*DM). bf16 epilogue. (4,8,5).
template <int MODE, int NT>
__global__ __launch_bounds__(512, 1)
void k_pipe(const ushort_t* __restrict__ A0, const ushort_t* __restrict__ B0,
            const ushort_t* __restrict__ A1, const ushort_t* __restrict__ B1,
            const float* __restrict__ gqw, const float* __restrict__ qbias,
            const float* __restrict__ vbias, const float* __restrict__ bo,
            void* __restrict__ OutV) {
  __shared__ __align__(16) ushort_t lsA[3][256 * 64];  // 3 x 32 KB
  __shared__ __align__(16) ushort_t lsB[3][128 * 64];  // 3 x 16 KB
  const int tid = threadIdx.x;
  const int w = tid >> 6, lane = tid & 63;
  const int m0 = blockIdx.x * 256, n0 = blockIdx.y * 128;
  const int b = (MODE == 0) ? (m0 >> 11) : 0;
  const int wr = w >> 2, wc = w & 3;  // 2x4 wave grid, per-wave 128x32 out

  // source pointers per mode
  const ushort_t *Aq, *Bq, *Av = nullptr, *Bv = nullptr;
  if constexpr (MODE == 0) {
    Aq = A0; Bq = B0; Av = A1; Bv = B1 + (size_t)b * (DM * DM);
  } else {
    const int z = blockIdx.z;
    Aq = z ? A1 + (size_t)(z - 1) * (DM * DM) : A0;
    Bq = z ? B1 : B0;
  }

  // staging geometry: chunk = 64 lanes x 16B = 8 rows of 128B (R9/R13-verified)
  const int subrow = lane >> 3;
  const int srcslot = (lane & 7) ^ subrow;
  size_t offA[4], offB[2];
#pragma unroll
  for (int p = 0; p < 4; ++p) {
    const int row = (4 * w + p) * 8 + subrow;           // 0..255
    offA[p] = (size_t)(m0 + row) * DM + srcslot * 8;
  }
#pragma unroll
  for (int p = 0; p < 2; ++p) {
    const int row = (2 * w + p) * 8 + subrow;           // 0..127
    offB[p] = (size_t)(n0 + row) * DM + srcslot * 8;
  }

  // ds_read fragment offsets: row*64 + (((kh*4+g)^(row&7))*8)  (conflicts=0)
  const int g = lane >> 4, l7 = lane & 7, l15 = lane & 15;
  int aoff[2][8], boff[2][2];
#pragma unroll
  for (int kh = 0; kh < 2; ++kh) {
#pragma unroll
    for (int i = 0; i < 8; ++i) {
      const int ra = wr * 128 + i * 16 + l15;
      aoff[kh][i] = ra * 64 + (((kh * 4 + g) ^ l7) * 8);
    }
#pragma unroll
    for (int j = 0; j < 2; ++j) {
      const int rb = wc * 32 + j * 16 + l15;
      boff[kh][j] = rb * 64 + (((kh * 4 + g) ^ l7) * 8);
    }
  }

  f32x4 acc[8][2];
#pragma unroll
  for (int i = 0; i < 8; ++i)
#pragma unroll
    for (int j = 0; j < 2; ++j) acc[i][j] = (f32x4){0.f, 0.f, 0.f, 0.f};

  auto SRC = [&](int tt, const ushort_t*& Ab, const ushort_t*& Bb, int& k0) {
    if (MODE == 0 && tt >= NT / 2) { Ab = Av; Bb = Bv; k0 = (tt - NT / 2) * 64; }
    else                           { Ab = Aq; Bb = Bq; k0 = tt * 64; }
  };
  auto STAGE_H0 = [&](int tt, int buf) {   // A chunks p=0,1 + B chunk p=0
    const ushort_t *Ab, *Bb; int k0; SRC(tt, Ab, Bb, k0);
    GLL(Ab + offA[0] + k0, &lsA[buf][(4 * w + 0) * 512]);
    GLL(Ab + offA[1] + k0, &lsA[buf][(4 * w + 1) * 512]);
    GLL(Bb + offB[0] + k0, &lsB[buf][(2 * w + 0) * 512]);
  };
  auto STAGE_H1 = [&](int tt, int buf) {   // A chunks p=2,3 + B chunk p=1
    const ushort_t *Ab, *Bb; int k0; SRC(tt, Ab, Bb, k0);
    GLL(Ab + offA[2] + k0, &lsA[buf][(4 * w + 2) * 512]);
    GLL(Ab + offA[3] + k0, &lsA[buf][(4 * w + 3) * 512]);
    GLL(Bb + offB[1] + k0, &lsB[buf][(2 * w + 1) * 512]);
  };
  auto READF = [&](bf16x8 (&av)[8], bf16x8 (&bv)[2], int cur, int kh) {
#pragma unroll
    for (int i = 0; i < 8; ++i) av[i] = *(const bf16x8*)(&lsA[cur][aoff[kh][i]]);
#pragma unroll
    for (int j = 0; j < 2; ++j) bv[j] = *(const bf16x8*)(&lsB[cur][boff[kh][j]]);
  };
  auto DOMFMA = [&](bf16x8 (&av)[8], bf16x8 (&bv)[2]) {
    __builtin_amdgcn_s_setprio(1);
#pragma unroll
    for (int i = 0; i < 8; ++i)
#pragma unroll
      for (int j = 0; j < 2; ++j)
        acc[i][j] = __builtin_amdgcn_mfma_f32_16x16x32_bf16(av[i], bv[j], acc[i][j], 0, 0, 0);
    __builtin_amdgcn_s_setprio(0);
  };

  bf16x8 avA[8], bvA[2], avB[8], bvB[2];

  // prologue: stage tiles 0,1; wait tile0 (12 outstanding -> <=6); read (0,0)
  STAGE_H0(0, 0); STAGE_H1(0, 0);
  STAGE_H0(1, 1); STAGE_H1(1, 1);
  asm volatile("s_waitcnt vmcnt(6)" ::: "memory");
  __builtin_amdgcn_s_barrier();
  READF(avA, bvA, 0, 0);

#pragma unroll 1
  for (int t = 0; t < NT; ++t) {
    const int cur = t % 3, nb = (t + 2) % 3, nxt = (t + 1) % 3;
    // ---- phase 0: read (t,1) ahead; stage H0(t+2); MFMA regs (t,0) ----
    READF(avB, bvB, cur, 1);
    if (t + 2 < NT) STAGE_H0(t + 2, nb);
    DOMFMA(avA, bvA);
    // ---- phase 1: sync tile t+1; read (t+1,0) ahead; stage H1(t+2);
    //      MFMA regs (t,1) ----
    if (t + 1 < NT) {
      // loads newer than tile t+1 = H0(t+2)'s 3 (if staged)
      if (t + 2 < NT) { asm volatile("s_waitcnt vmcnt(3)\n\ts_barrier" ::: "memory"); }
      else            { asm volatile("s_waitcnt vmcnt(0)\n\ts_barrier" ::: "memory"); }
      READF(avA, bvA, nxt, 0);
      if (t + 2 < NT) STAGE_H1(t + 2, nb);
    }
    DOMFMA(avB, bvB);
  }

  // epilogue: C/D layout col = lane&15, row = (lane>>4)*4 + reg
  const int lr = (lane >> 4) * 4, lc = lane & 15;
  const int rbase = m0 + wr * 128, cbase = n0 + wc * 32;
  if constexpr (MODE == 0) {
    float* Out = (float*)OutV;
#pragma unroll
    for (int j = 0; j < 2; ++j) {
      const int col = cbase + j * 16 + lc;
      const float qbn = qbias[col];
      const float cb = vbias[b * DM + col] + bo[col];
#pragma unroll
      for (int i = 0; i < 8; ++i)
#pragma unroll
        for (int r = 0; r < 4; ++r) {
          const int row = rbase + i * 16 + lr + r;
          Out[(size_t)row * DM + col] = acc[i][j][r] + gqw[row & (SEQ - 1)] * qbn + cb;
        }
    }
  } else {
    ushort_t* Out = (ushort_t*)OutV + (size_t)blockIdx.z * (DM * DM);
#pragma unroll
    for (int j = 0; j < 2; ++j) {
      const int col = cbase + j * 16 + lc;
#pragma unroll
      for (int i = 0; i < 8; ++i)
#pragma unroll
        for (int r = 0; r < 4; ++r) {
          const int row = rbase + i * 16 + lr + r;
          Out[(size_t)row * DM + col] = f2bf(acc[i][j][r]);
        }
    }
  }
}

// ---------------------------------------------------------------------------
extern "C" void kernel_launch(void* const* d_in, const int* in_sizes, int n_in,
                              void* d_out, int out_size, void* d_ws, size_t ws_size,
                              hipStream_t stream) {
  // input order: v k q mask wq bq wk bk wv bv gqw gkw wo bo
  const float* v   = (const float*)d_in[0];
  const float* k   = (const float*)d_in[1];
  const float* q   = (const float*)d_in[2];
  const float* wq  = (const float*)d_in[4];
  const float* bq  = (const float*)d_in[5];
  const float* wk  = (const float*)d_in[6];
  const float* bk  = (const float*)d_in[7];
  const float* wv  = (const float*)d_in[8];
  const float* bv  = (const float*)d_in[9];
  const float* gqw = (const float*)d_in[10];
  const float* gkw = (const float*)d_in[11];
  const float* wo  = (const float*)d_in[12];
  const float* bo  = (const float*)d_in[13];
  float* out = (float*)d_out;
  float* wsf = (float*)d_ws;

  // fp32 scratch: [qr kr qacc kacc | G | qbias | vbias | gk]
  float* qr    = wsf + 0;
  float* kr    = wsf + 4096;
  float* qacc  = wsf + 8192;
  float* kacc  = wsf + 12288;
  float* G     = wsf + 16384;   // 2 floats
  float* qbias = wsf + 16640;   // 1024
  float* vbias = wsf + 17664;   // 4096
  float* gk    = wsf + 21760;   // 4096 (fully written by k_gfin)
  // bf16 scratch at byte offset 128 KiB
  ushort_t* b16  = (ushort_t*)((char*)d_ws + (1 << 17));
  ushort_t* qb   = b16;                                 // 16MB gqw-scaled
  ushort_t* vb   = qb + (size_t)M_TOT * DM;             // 16MB
  ushort_t* wqB  = vb + (size_t)M_TOT * DM;             // 2MB
  ushort_t* wvB  = wqB + (size_t)DM * DM;               // 2MB
  ushort_t* woT  = wvB + (size_t)DM * DM;               // 2MB [N][K]
  ushort_t* WqoT = woT + (size_t)DM * DM;               // 2MB
  ushort_t* WvbT = WqoT + (size_t)DM * DM;              // 8MB [4][N][K] (contiguous after WqoT)
  // dead d_out space hosts transient buffers (all consumed before k_pipe<0> writes):
  ushort_t* wogT = (ushort_t*)out;       // [0, 8MB)
  float* pq = out + (1 << 22);           // [16, 20MB): 256 slots x 4 x 1024 f32
  float* pk = pq + (1 << 20);            // [20, 24MB)

  hipMemsetAsync(d_ws, 0, 21760 * sizeof(float), stream);

  // weight preps
  k_conv<<<dim3((DM * DM / 8) / 256, 2), 256, 0, stream>>>(wq, wqB, wv, wvB);
  k_trans<<<dim3(32, 32), 256, 0, stream>>>(wo, woT);

  // data reductions + bf16 conversions (atomic-free partials)
  k_reduce<<<dim3(BATCH, SEQ / 8), 256, 0, stream>>>(q, k, v, gqw, gkw, pq, pk, G, qb, vb);
  k_rsum<<<dim3(BATCH, DM / 256, 8), 256, 0, stream>>>(pq, pk, qr, kr);

  // gk
  k_gpart<<<dim3(DM / 256, DM / 32), 256, 0, stream>>>(wq, wk, qr, kr, qacc, kacc);
  k_gfin<<<(BATCH * DM) / 256, 256, 0, stream>>>(qacc, kacc, bq, bk, G, gk);

  // composed-weight preps
  k_wog<<<(BATCH * DM * DM / 8) / 256, 256, 0, stream>>>(woT, gk, wogT);
  k_bias<<<dim3(DM / 256, DM / 32), 256, 0, stream>>>(wo, bq, bv, gk, qbias, vbias);

  // small GEMMs (pipelined): z=0 WqoT, z>0 WvbT[z-1] (Out = WqoT + z*DM*DM)
  k_pipe<1, 16><<<dim3(4, 8, 5), 512, 0, stream>>>(
      woT, wqB, wogT, wvB, nullptr, nullptr, nullptr, nullptr, WqoT);

  // the one big GEMM -> out (pipelined)
  k_pipe<0, 32><<<dim3(M_TOT / 256, DM / 128), 512, 0, stream>>>(
      qb, WqoT, vb, WvbT, gqw, qbias, vbias, bo, out);
}